// Round 2
// baseline (20678.950 us; speedup 1.0000x reference)
//
#include <hip/hip_runtime.h>
#include <cstdint>

#define NN 128
#define LL 512
#define DD 512
#define HH 1024

// ---------------- Kernel A: s[n,l] = sum_d X[n,l,d] ----------------
// one wave (64 lanes) per row of 512; 4 rows per 256-thread block
__global__ __launch_bounds__(256)
void sum_rows_kernel(const float* __restrict__ X, float* __restrict__ s) {
  int row  = blockIdx.x * 4 + (threadIdx.x >> 6);
  int lane = threadIdx.x & 63;
  const float* x = X + (size_t)row * DD + lane * 8;
  float4 a = *(const float4*)x;
  float4 b = *(const float4*)(x + 4);
  float v = (a.x + a.y) + (a.z + a.w) + (b.x + b.y) + (b.z + b.w);
#pragma unroll
  for (int off = 32; off > 0; off >>= 1) v += __shfl_down(v, off, 64);
  if (lane == 0) s[row] = v;
}

__device__ __forceinline__ float sigf(float x) {
  return 1.0f / (1.0f + __expf(-x));
}

// ---------------- Kernel B: one LSTM timestep ----------------
// block: 128 threads. tile: 16 samples x 16 h-cols x 4 gates.
// grid: (64 hc-tiles, 8 n-tiles) = 512 blocks -> 2 blocks/CU.
// thread: 2 samples x 1 hc x 4 gates = 8 accumulators.
// LDS rows padded to 68 floats: 272B row stride = 16B-aligned, banks
// step by 4 per row -> <=2-way aliasing (free).
__global__ __launch_bounds__(128)
void lstm_step_kernel(const float* __restrict__ s,
    const float* __restrict__ Wi, const float* __restrict__ Wf,
    const float* __restrict__ Wg, const float* __restrict__ Wo,
    const float* __restrict__ lami, const float* __restrict__ lamf,
    const float* __restrict__ lamg, const float* __restrict__ lamo,
    const float* __restrict__ bvi, const float* __restrict__ bvf,
    const float* __restrict__ bvg, const float* __restrict__ bvo,
    const float* __restrict__ bi, const float* __restrict__ bf,
    const float* __restrict__ bg, const float* __restrict__ bo,
    float* __restrict__ out, float* __restrict__ cbuf, int t)
{
  __shared__ float hs[16][68];    // h tile   [n-sub][k]
  __shared__ float ws4[64][68];   // W tile   [g*16+hc-sub][k]
  const int tid = threadIdx.x;
  const int hc0 = blockIdx.x << 4;
  const int n0  = blockIdx.y << 4;
  const int th  = tid & 15;       // hc-sub
  const int tn  = tid >> 4;       // 0..7 -> 2 samples each

  float acc[4][2] = {{0.f,0.f},{0.f,0.f},{0.f,0.f},{0.f,0.f}};

  if (t > 0) {
    const int lr = tid >> 4;          // staging row-sub 0..7
    const int lc = (tid & 15) << 2;   // staging col (float4 granularity)
    const float* __restrict__ hprev = out + (size_t)(t - 1) * HH;
    for (int k0 = 0; k0 < HH; k0 += 64) {
      // stage h tile: 16 rows x 64 cols (coalesced: 16 lanes x float4 per row)
#pragma unroll
      for (int p = 0; p < 2; ++p) {
        int r = p * 8 + lr;
        const float* src = hprev + (size_t)(n0 + r) * (LL * HH) + k0 + lc;
        *(float4*)&hs[r][lc] = *(const float4*)src;
      }
      // stage W tile: 64 rows (4 gates x 16 hc) x 64 cols
#pragma unroll
      for (int p = 0; p < 8; ++p) {
        const float* Wsel = (p < 2) ? Wi : (p < 4) ? Wf : (p < 6) ? Wg : Wo;
        int rl = (p & 1) * 8 + lr;        // row within gate 0..15
        int r  = (p >> 1) * 16 + rl;      // row in ws4
        const float* src = Wsel + ((size_t)(hc0 + rl) << 10) + k0 + lc;
        *(float4*)&ws4[r][lc] = *(const float4*)src;
      }
      __syncthreads();
      const int tn2 = tn << 1;
#pragma unroll
      for (int kk = 0; kk < 64; kk += 4) {
        float4 h0 = *(const float4*)&hs[tn2][kk];       // 16-lane broadcast
        float4 h1 = *(const float4*)&hs[tn2 + 1][kk];
#pragma unroll
        for (int g = 0; g < 4; ++g) {
          float4 w = *(const float4*)&ws4[(g << 4) + th][kk];
          acc[g][0] = fmaf(h0.w, w.w, fmaf(h0.z, w.z,
                      fmaf(h0.y, w.y, fmaf(h0.x, w.x, acc[g][0]))));
          acc[g][1] = fmaf(h1.w, w.w, fmaf(h1.z, w.z,
                      fmaf(h1.y, w.y, fmaf(h1.x, w.x, acc[g][1]))));
        }
      }
      __syncthreads();
    }
  }

  // epilogue: gates -> c,h ; write h into out[:, t, :] (h history IS the output)
  const int hc = hc0 + th;
  const float li = lami[hc], lf = lamf[hc], lg = lamg[hc], lo = lamo[hc];
  const float ci = bvi[hc] + bi[hc];
  const float cf = bvf[hc] + bf[hc];
  const float cg = bvg[hc] + bg[hc];
  const float co = bvo[hc] + bo[hc];
#pragma unroll
  for (int i = 0; i < 2; ++i) {
    int n = n0 + (tn << 1) + i;
    float sv = s[n * LL + t];
    float gi = sigf(sv * li + ci + acc[0][i]);
    float gf = sigf(sv * lf + cf + acc[1][i]);
    float gg = sigf(sv * lg + cg + acc[2][i]);
    float go = sigf(sv * lo + co + acc[3][i]);
    float cold = (t > 0) ? cbuf[n * HH + hc] : 0.f;  // t=0 never reads poisoned ws
    float cn = gf * cold + gi * gg;
    float hn = go * sigf(cn);
    cbuf[n * HH + hc] = cn;
    out[(size_t)n * (LL * HH) + (size_t)t * HH + hc] = hn;
  }
}

extern "C" void kernel_launch(void* const* d_in, const int* in_sizes, int n_in,
                              void* d_out, int out_size, void* d_ws, size_t ws_size,
                              hipStream_t stream) {
  const float* X    = (const float*)d_in[0];
  // input order per gate g in {i,f,g,o}: lam, binv, W, b at 1+4g..4+4g
  const float* lami = (const float*)d_in[1];
  const float* bvi  = (const float*)d_in[2];
  const float* Wi   = (const float*)d_in[3];
  const float* bi   = (const float*)d_in[4];
  const float* lamf = (const float*)d_in[5];
  const float* bvf  = (const float*)d_in[6];
  const float* Wf   = (const float*)d_in[7];
  const float* bf   = (const float*)d_in[8];
  const float* lamg = (const float*)d_in[9];
  const float* bvg  = (const float*)d_in[10];
  const float* Wg   = (const float*)d_in[11];
  const float* bg   = (const float*)d_in[12];
  const float* lamo = (const float*)d_in[13];
  const float* bvo  = (const float*)d_in[14];
  const float* Wo   = (const float*)d_in[15];
  const float* bo   = (const float*)d_in[16];

  float* out  = (float*)d_out;
  float* cbuf = (float*)d_ws;                        // 128*1024 f32 = 512 KB
  float* sbuf = (float*)d_ws + (size_t)NN * HH;      // 128*512  f32 = 256 KB

  // s[n,l] = sum_d X[n,l,d]
  sum_rows_kernel<<<(NN * LL) / 4, 256, 0, stream>>>(X, sbuf);

  dim3 grid(HH / 16, NN / 16);   // (64, 8)
  for (int t = 0; t < LL; ++t) {
    lstm_step_kernel<<<grid, 128, 0, stream>>>(sbuf,
        Wi, Wf, Wg, Wo,
        lami, lamf, lamg, lamo,
        bvi, bvf, bvg, bvo,
        bi, bf, bg, bo,
        out, cbuf, t);
  }
}

// Round 3
// 7594.829 us; speedup vs baseline: 2.7228x; 2.7228x over previous
//
#include <hip/hip_runtime.h>
#include <cstdint>
#include <cstddef>

#define NN 128
#define LL 512
#define DD 512
#define HH 1024
#define NJ 4096            // packed gate cols, j = 4*hc + g
#define AK 2048            // A/B buffer row length in elements (hi | lo)
#define KTOT 3072          // split-GEMM K  (hh | hl | lh)
#define BKC 128            // K per chunk
#define NCHUNK (KTOT / BKC)

typedef __attribute__((ext_vector_type(8))) short short8;
typedef __attribute__((ext_vector_type(4))) float f32x4;

__device__ __forceinline__ unsigned short f2bf(float x) {
  union { float f; unsigned u; } v; v.f = x;
  unsigned r = v.u + 0x7FFFu + ((v.u >> 16) & 1u);
  return (unsigned short)(r >> 16);
}
__device__ __forceinline__ float bf2f(unsigned short b) {
  union { unsigned u; float f; } v; v.u = ((unsigned)b) << 16;
  return v.f;
}
__device__ __forceinline__ float sigf(float x) { return 1.0f / (1.0f + __expf(-x)); }

__device__ __forceinline__ void glds16(const void* g, const void* l) {
  __builtin_amdgcn_global_load_lds(
      (const __attribute__((address_space(1))) unsigned int*)g,
      (__attribute__((address_space(3))) unsigned int*)l, 16, 0, 0);
}

// ---------------- s[n,l] = sum_d X[n,l,d] ----------------
__global__ __launch_bounds__(256)
void sum_rows_kernel(const float* __restrict__ X, float* __restrict__ s) {
  int row  = blockIdx.x * 4 + (threadIdx.x >> 6);
  int lane = threadIdx.x & 63;
  const float* x = X + (size_t)row * DD + lane * 8;
  float4 a = *(const float4*)x;
  float4 b = *(const float4*)(x + 4);
  float v = (a.x + a.y) + (a.z + a.w) + (b.x + b.y) + (b.z + b.w);
#pragma unroll
  for (int off = 32; off > 0; off >>= 1) v += __shfl_down(v, off, 64);
  if (lane == 0) s[row] = v;
}

// ---------------- split W into bf16 hi|lo, gate-interleaved rows ----------------
__global__ __launch_bounds__(256)
void wsplit_kernel(const float* __restrict__ Wi, const float* __restrict__ Wf,
                   const float* __restrict__ Wg, const float* __restrict__ Wo,
                   unsigned short* __restrict__ B) {
  int idx = blockIdx.x * 256 + threadIdx.x;    // NJ*128 threads
  int j = idx >> 7;
  int k = (idx & 127) << 3;
  int hc = j >> 2, g = j & 3;
  const float* W = (g == 0) ? Wi : (g == 1) ? Wf : (g == 2) ? Wg : Wo;
  const float4 x0 = *(const float4*)(W + (size_t)hc * HH + k);
  const float4 x1 = *(const float4*)(W + (size_t)hc * HH + k + 4);
  float xv[8] = {x0.x, x0.y, x0.z, x0.w, x1.x, x1.y, x1.z, x1.w};
  unsigned short* dhi = B + (size_t)j * AK + k;
  unsigned short* dlo = dhi + 1024;
#pragma unroll
  for (int e = 0; e < 8; ++e) {
    unsigned short hi = f2bf(xv[e]);
    dhi[e] = hi;
    dlo[e] = f2bf(xv[e] - bf2f(hi));
  }
}

// ---------------- pack lambda / (binv+b) gate-interleaved ----------------
__global__ __launch_bounds__(256)
void pack_kernel(const float* li, const float* lf, const float* lg, const float* lo_,
                 const float* bvi, const float* bvf, const float* bvg, const float* bvo,
                 const float* bi, const float* bf_, const float* bg, const float* bo,
                 float* __restrict__ lamP, float* __restrict__ biasP) {
  int j = blockIdx.x * 256 + threadIdx.x;
  int hc = j >> 2, g = j & 3;
  const float* lam = (g == 0) ? li : (g == 1) ? lf : (g == 2) ? lg : lo_;
  const float* bv  = (g == 0) ? bvi : (g == 1) ? bvf : (g == 2) ? bvg : bvo;
  const float* bb  = (g == 0) ? bi : (g == 1) ? bf_ : (g == 2) ? bg : bo;
  lamP[j] = lam[hc];
  biasP[j] = bv[hc] + bb[hc];
}

// ---------------- t = 0 (h=0, c=0: no GEMM) ----------------
__global__ __launch_bounds__(256)
void t0_kernel(const float* __restrict__ sbuf, const float* __restrict__ lamP,
               const float* __restrict__ biasP, float* __restrict__ out,
               float* __restrict__ cbuf, unsigned short* __restrict__ A0) {
  int id = blockIdx.x * 256 + threadIdx.x;   // NN*HH threads
  int n = id >> 10, hc = id & 1023;
  float sv = sbuf[(size_t)n * LL];           // t = 0
  float4 lam = *(const float4*)(lamP + 4 * hc);
  float4 bia = *(const float4*)(biasP + 4 * hc);
  float vi = sigf(sv * lam.x + bia.x);
  float vg = sigf(sv * lam.z + bia.z);
  float vo = sigf(sv * lam.w + bia.w);
  float cn = vi * vg;                        // f*0 + i*g
  float hn = vo * sigf(cn);
  cbuf[n * HH + hc] = cn;
  out[(size_t)n * (LL * HH) + hc] = hn;
  unsigned short hi = f2bf(hn);
  A0[(size_t)n * AK + hc] = hi;
  A0[(size_t)n * AK + 1024 + hc] = f2bf(hn - bf2f(hi));
}

// ---------------- one LSTM step: bf16x3 split MFMA GEMM + fused gates ----------------
// grid 256 blocks (XCD-contiguous N), block 256 thr = 4 waves (2M x 2N of 16x32)
__global__ __launch_bounds__(256)
void step_kernel(const unsigned short* __restrict__ Aprev,
                 const unsigned short* __restrict__ Bbuf,
                 const float* __restrict__ sbuf, const float* __restrict__ lamP,
                 const float* __restrict__ biasP, float* __restrict__ out,
                 float* __restrict__ cbuf, unsigned short* __restrict__ Acur, int t)
{
  __shared__ alignas(16) short Asm[2][32 * BKC];   // 8 KB x2
  __shared__ alignas(16) short Bsm[2][64 * BKC];   // 16 KB x2

  const int tid = threadIdx.x;
  const int ln  = tid & 63;
  const int wv  = tid >> 6;          // 0..3
  const int wm  = wv & 1;
  const int wn  = wv >> 1;

  // XCD-contiguous work mapping: XCD x owns Nt in [8x, 8x+8)
  const int bid = blockIdx.x;
  const int w   = (bid & 7) * 32 + (bid >> 3);
  const int Nt  = w >> 2;            // 0..63
  const int Mt  = w & 3;             // 0..3
  const int n0  = Mt * 32;
  const int j0  = Nt * 64;

  // --- staging precompute: 6 gload_lds pieces per wave (A:8, B:16 total) ---
  const char* srcb[6];
  int ldsoff[6];
  bool isA[6];
  {
    const int ps = ln & 15;            // phys 16B slot this lane writes
    const int rr = ln >> 4;            // row within 4-row piece
#pragma unroll
    for (int i = 0; i < 6; ++i) {
      int p = wv * 6 + i;
      if (p < 8) {
        int row = p * 4 + rr;                       // 0..31
        int sp  = (ps & 8) | ((ps ^ row) & 7);      // inverse-swizzled source slot
        srcb[i] = (const char*)(Aprev + (size_t)(n0 + row) * AK + sp * 8);
        ldsoff[i] = p * 512;
        isA[i] = true;
      } else {
        int q = p - 8;
        int row = q * 4 + rr;                       // 0..63
        int sp  = (ps & 8) | ((ps ^ row) & 7);
        srcb[i] = (const char*)(Bbuf + (size_t)(j0 + row) * AK + sp * 8);
        ldsoff[i] = q * 512;
        isA[i] = false;
      }
    }
  }

  // --- fragment read offsets (swizzled), elements within one buffer plane ---
  int aoff[4], b0off[4], b1off[4];
  {
    const int rA  = wm * 16 + (ln & 15);
    const int rB0 = wn * 32 + (ln & 15);
    const int rB1 = rB0 + 16;
    const int hs  = ln >> 4;
#pragma unroll
    for (int ks = 0; ks < 4; ++ks) {
      int s = 4 * ks + hs;
      aoff[ks]  = rA  * BKC + (((s & 8) | ((s ^ rA ) & 7)) << 3);
      b0off[ks] = rB0 * BKC + (((s & 8) | ((s ^ rB0) & 7)) << 3);
      b1off[ks] = rB1 * BKC + (((s & 8) | ((s ^ rB1) & 7)) << 3);
    }
  }

  f32x4 acc0 = {0.f, 0.f, 0.f, 0.f};
  f32x4 acc1 = {0.f, 0.f, 0.f, 0.f};

  auto stage = [&](int chunk, int buf) {
    // per-chunk uniform source column offset (bytes); segments are chunk-aligned
    const int coA = ((chunk < 8)  ? chunk * BKC : chunk * BKC - 1024) * 2;
    const int coB = ((chunk < 16) ? chunk * BKC : chunk * BKC - 2048) * 2;
#pragma unroll
    for (int i = 0; i < 6; ++i) {
      if (isA[i]) glds16(srcb[i] + coA, &Asm[buf][ldsoff[i]]);
      else        glds16(srcb[i] + coB, &Bsm[buf][ldsoff[i]]);
    }
  };

  stage(0, 0);
  __syncthreads();

  for (int chunk = 0; chunk < NCHUNK; ++chunk) {
    const int buf = chunk & 1;
    if (chunk + 1 < NCHUNK) stage(chunk + 1, buf ^ 1);
#pragma unroll
    for (int ks = 0; ks < 4; ++ks) {
      short8 av = *(const short8*)&Asm[buf][aoff[ks]];
      short8 b0 = *(const short8*)&Bsm[buf][b0off[ks]];
      short8 b1 = *(const short8*)&Bsm[buf][b1off[ks]];
      acc0 = __builtin_amdgcn_mfma_f32_16x16x32_bf16(av, b0, acc0, 0, 0, 0);
      acc1 = __builtin_amdgcn_mfma_f32_16x16x32_bf16(av, b1, acc1, 0, 0, 0);
    }
    __syncthreads();
  }

  // ---- epilogue: fuse 4 gates (adjacent lanes) -> c,h ; emit h, c, h_hi/h_lo ----
  const int mbase = n0 + wm * 16 + (ln >> 4) * 4;
  float sv[4];
#pragma unroll
  for (int r = 0; r < 4; ++r) sv[r] = sbuf[(size_t)(mbase + r) * LL + t];

#pragma unroll
  for (int nf = 0; nf < 2; ++nf) {
    const int j = j0 + wn * 32 + nf * 16 + (ln & 15);
    const float lamv = lamP[j];
    const float biav = biasP[j];
#pragma unroll
    for (int r = 0; r < 4; ++r) {
      float a = (nf == 0) ? acc0[r] : acc1[r];
      float v = sigf(a + sv[r] * lamv + biav);
      const int base = ln & ~3;
      float vi = __shfl(v, base + 0, 64);
      float vf = __shfl(v, base + 1, 64);
      float vg = __shfl(v, base + 2, 64);
      float vo = __shfl(v, base + 3, 64);
      if ((ln & 3) == 0) {
        const int hc = j >> 2;
        const int m = mbase + r;
        float cold = cbuf[m * HH + hc];
        float cn = vf * cold + vi * vg;
        float hn = vo * sigf(cn);
        cbuf[m * HH + hc] = cn;
        out[(size_t)m * (LL * HH) + (size_t)t * HH + hc] = hn;
        unsigned short hi2 = f2bf(hn);
        Acur[(size_t)m * AK + hc] = hi2;
        Acur[(size_t)m * AK + 1024 + hc] = f2bf(hn - bf2f(hi2));
      }
    }
  }
}

extern "C" void kernel_launch(void* const* d_in, const int* in_sizes, int n_in,
                              void* d_out, int out_size, void* d_ws, size_t ws_size,
                              hipStream_t stream) {
  const float* X    = (const float*)d_in[0];
  const float* lami = (const float*)d_in[1];
  const float* bvi  = (const float*)d_in[2];
  const float* Wi   = (const float*)d_in[3];
  const float* bi   = (const float*)d_in[4];
  const float* lamf = (const float*)d_in[5];
  const float* bvf  = (const float*)d_in[6];
  const float* Wf   = (const float*)d_in[7];
  const float* bf_  = (const float*)d_in[8];
  const float* lamg = (const float*)d_in[9];
  const float* bvg  = (const float*)d_in[10];
  const float* Wg   = (const float*)d_in[11];
  const float* bg   = (const float*)d_in[12];
  const float* lamo = (const float*)d_in[13];
  const float* bvo  = (const float*)d_in[14];
  const float* Wo   = (const float*)d_in[15];
  const float* bo   = (const float*)d_in[16];

  float* out  = (float*)d_out;

  // workspace layout (~18.2 MB)
  float* cbuf  = (float*)d_ws;                         // 128*1024 f32
  float* sbuf  = cbuf + (size_t)NN * HH;               // 128*512  f32
  float* lamP  = sbuf + (size_t)NN * LL;               // 4096 f32
  float* biasP = lamP + NJ;                            // 4096 f32
  unsigned short* A0 = (unsigned short*)(biasP + NJ);  // 128*2048 bf16
  unsigned short* A1 = A0 + (size_t)NN * AK;           // 128*2048 bf16
  unsigned short* Bb = A1 + (size_t)NN * AK;           // 4096*2048 bf16 (16 MB)

  sum_rows_kernel<<<(NN * LL) / 4, 256, 0, stream>>>(X, sbuf);
  wsplit_kernel<<<(NJ * 128) / 256, 256, 0, stream>>>(Wi, Wf, Wg, Wo, Bb);
  pack_kernel<<<NJ / 256, 256, 0, stream>>>(lami, lamf, lamg, lamo,
                                            bvi, bvf, bvg, bvo,
                                            bi, bf_, bg, bo, lamP, biasP);
  t0_kernel<<<(NN * HH) / 256, 256, 0, stream>>>(sbuf, lamP, biasP, out, cbuf, A0);

  for (int t = 1; t < LL; ++t) {
    const unsigned short* Ap = (t & 1) ? A0 : A1;
    unsigned short* Ac = (t & 1) ? (unsigned short*)A1 : A0;
    step_kernel<<<256, 256, 0, stream>>>(Ap, Bb, sbuf, lamP, biasP, out, cbuf, Ac, t);
  }
}

// Round 4
// 6487.266 us; speedup vs baseline: 3.1876x; 1.1707x over previous
//
#include <hip/hip_runtime.h>
#include <cstdint>
#include <cstddef>

#define NN 128
#define LL 512
#define DD 512
#define HH 1024
#define NJ 4096            // packed gate cols, j = 4*hc + g
#define AK 2048            // A/B row length in bf16 elems (hi | lo planes)
#define NCH 8              // physical K chunks
#define CK 128             // k-width per chunk (per plane)

// LDS plane offsets (shorts) within one 48KB buffer
#define AHI 0
#define ALO 4096
#define BHI 8192
#define BLO 16384

typedef __attribute__((ext_vector_type(8))) short short8;
typedef __attribute__((ext_vector_type(4))) float f32x4;

__device__ __forceinline__ unsigned short f2bf(float x) {
  union { float f; unsigned u; } v; v.f = x;
  unsigned r = v.u + 0x7FFFu + ((v.u >> 16) & 1u);
  return (unsigned short)(r >> 16);
}
__device__ __forceinline__ float bf2f(unsigned short b) {
  union { unsigned u; float f; } v; v.u = ((unsigned)b) << 16;
  return v.f;
}
__device__ __forceinline__ float sigf(float x) { return 1.0f / (1.0f + __expf(-x)); }

__device__ __forceinline__ void glds16(const void* g, const void* l) {
  __builtin_amdgcn_global_load_lds(
      (const __attribute__((address_space(1))) unsigned int*)g,
      (__attribute__((address_space(3))) unsigned int*)l, 16, 0, 0);
}

// ---------------- sT[l*NN + n] = sum_d X[n,l,d] (transposed for epilogue) ----
__global__ __launch_bounds__(256)
void sum_rows_kernel(const float* __restrict__ X, float* __restrict__ sT) {
  int row  = blockIdx.x * 4 + (threadIdx.x >> 6);
  int lane = threadIdx.x & 63;
  const float* x = X + (size_t)row * DD + lane * 8;
  float4 a = *(const float4*)x;
  float4 b = *(const float4*)(x + 4);
  float v = (a.x + a.y) + (a.z + a.w) + (b.x + b.y) + (b.z + b.w);
#pragma unroll
  for (int off = 32; off > 0; off >>= 1) v += __shfl_down(v, off, 64);
  if (lane == 0) {
    int n = row >> 9, l = row & 511;
    sT[l * NN + n] = v;
  }
}

// ---------------- split W into bf16 hi|lo, gate-interleaved rows ----------------
__global__ __launch_bounds__(256)
void wsplit_kernel(const float* __restrict__ Wi, const float* __restrict__ Wf,
                   const float* __restrict__ Wg, const float* __restrict__ Wo,
                   unsigned short* __restrict__ B) {
  int idx = blockIdx.x * 256 + threadIdx.x;    // NJ*128 threads
  int j = idx >> 7;
  int k = (idx & 127) << 3;
  int hc = j >> 2, g = j & 3;
  const float* W = (g == 0) ? Wi : (g == 1) ? Wf : (g == 2) ? Wg : Wo;
  const float4 x0 = *(const float4*)(W + (size_t)hc * HH + k);
  const float4 x1 = *(const float4*)(W + (size_t)hc * HH + k + 4);
  float xv[8] = {x0.x, x0.y, x0.z, x0.w, x1.x, x1.y, x1.z, x1.w};
  unsigned short* dhi = B + (size_t)j * AK + k;
  unsigned short* dlo = dhi + 1024;
#pragma unroll
  for (int e = 0; e < 8; ++e) {
    unsigned short hi = f2bf(xv[e]);
    dhi[e] = hi;
    dlo[e] = f2bf(xv[e] - bf2f(hi));
  }
}

// ---------------- pack lambda / (binv+b) gate-interleaved ----------------
__global__ __launch_bounds__(256)
void pack_kernel(const float* li, const float* lf, const float* lg, const float* lo_,
                 const float* bvi, const float* bvf, const float* bvg, const float* bvo,
                 const float* bi, const float* bf_, const float* bg, const float* bo,
                 float* __restrict__ lamP, float* __restrict__ biasP) {
  int j = blockIdx.x * 256 + threadIdx.x;
  int hc = j >> 2, g = j & 3;
  const float* lam = (g == 0) ? li : (g == 1) ? lf : (g == 2) ? lg : lo_;
  const float* bv  = (g == 0) ? bvi : (g == 1) ? bvf : (g == 2) ? bvg : bvo;
  const float* bb  = (g == 0) ? bi : (g == 1) ? bf_ : (g == 2) ? bg : bo;
  lamP[j] = lam[hc];
  biasP[j] = bv[hc] + bb[hc];
}

// ---------------- t = 0 (h=0, c=0: no GEMM) ----------------
__global__ __launch_bounds__(256)
void t0_kernel(const float* __restrict__ sT, const float* __restrict__ lamP,
               const float* __restrict__ biasP, float* __restrict__ out,
               float* __restrict__ cbuf, unsigned short* __restrict__ A0) {
  int id = blockIdx.x * 256 + threadIdx.x;   // NN*HH threads
  int n = id >> 10, hc = id & 1023;
  float sv = sT[n];                          // t = 0 slice
  float4 lam = *(const float4*)(lamP + 4 * hc);
  float4 bia = *(const float4*)(biasP + 4 * hc);
  float vi = sigf(sv * lam.x + bia.x);
  float vg = sigf(sv * lam.z + bia.z);
  float vo = sigf(sv * lam.w + bia.w);
  float cn = vi * vg;
  float hn = vo * sigf(cn);
  cbuf[n * HH + hc] = cn;
  out[(size_t)n * (LL * HH) + hc] = hn;
  unsigned short hi = f2bf(hn);
  A0[(size_t)n * AK + hc] = hi;
  A0[(size_t)n * AK + 1024 + hc] = f2bf(hn - bf2f(hi));
}

// ---------------- one LSTM step ----------------
// grid 256 blocks (XCD-swizzled), block 256 thr = 4 waves.
// block tile: 32 m x 64 j. wave tile: 32 m x 16 j (waves split j).
// K loop: 8 phys chunks of 128; per chunk stage {Ahi,Alo,Bhi,Blo} once,
// run all 3 Markidis products (hh, hl, lh) per fragment pair.
// Double-buffered LDS (2 x 48 KB) with counted vmcnt(12) + raw s_barrier.
__global__ __launch_bounds__(256, 1)
void step_kernel(const unsigned short* __restrict__ Aprev,
                 const unsigned short* __restrict__ Bbuf,
                 const float* __restrict__ sT, const float* __restrict__ lamP,
                 const float* __restrict__ biasP, float* __restrict__ out,
                 float* __restrict__ cbuf, unsigned short* __restrict__ Acur, int t)
{
  __shared__ alignas(16) short lds[2][24576];   // 48 KB x 2

  const int tid = threadIdx.x;
  const int ln  = tid & 63;
  const int w   = tid >> 6;          // wave 0..3

  // XCD-contiguous mapping: XCD x owns Nt in [8x, 8x+8)
  const int bid = blockIdx.x;
  const int wl  = (bid & 7) * 32 + (bid >> 3);
  const int Nt  = wl >> 2;           // 0..63  (j tile)
  const int Mt  = wl & 3;            // 0..3   (m tile)
  const int n0  = Mt * 32;
  const int j0  = Nt * 64;

  // --- staging piece table: 48 pieces of 1KB; wave w owns [12w, 12w+12) ---
  const char* srcb[12];
  int ldsoff[12];
  {
    const int ps = ln & 15;
    const int rr = ln >> 4;
#pragma unroll
    for (int i = 0; i < 12; ++i) {
      int p = w * 12 + i;
      const char* s; int off;
      if (p < 8)       { int r = p * 4 + rr;        int sp = (ps & 8) | ((ps ^ r) & 7);
                         s = (const char*)(Aprev + (size_t)(n0 + r) * AK + sp * 8);
                         off = AHI + p * 512; }
      else if (p < 16) { int r = (p - 8) * 4 + rr;  int sp = (ps & 8) | ((ps ^ r) & 7);
                         s = (const char*)(Aprev + (size_t)(n0 + r) * AK + 1024 + sp * 8);
                         off = ALO + (p - 8) * 512; }
      else if (p < 32) { int r = (p - 16) * 4 + rr; int sp = (ps & 8) | ((ps ^ r) & 7);
                         s = (const char*)(Bbuf + (size_t)(j0 + r) * AK + sp * 8);
                         off = BHI + (p - 16) * 512; }
      else             { int r = (p - 32) * 4 + rr; int sp = (ps & 8) | ((ps ^ r) & 7);
                         s = (const char*)(Bbuf + (size_t)(j0 + r) * AK + 1024 + sp * 8);
                         off = BLO + (p - 32) * 512; }
      srcb[i] = s; ldsoff[i] = off;
    }
  }

  // --- fragment read offsets (shorts, within a plane) ---
  int aoff[2][4], boff[4];
  {
#pragma unroll
    for (int mf = 0; mf < 2; ++mf)
#pragma unroll
      for (int sl = 0; sl < 4; ++sl) {
        int rA = mf * 16 + (ln & 15);
        int s  = sl * 4 + (ln >> 4);
        aoff[mf][sl] = rA * 128 + (((s & 8) | ((s ^ rA) & 7)) << 3);
      }
    int rB = w * 16 + (ln & 15);
#pragma unroll
    for (int sl = 0; sl < 4; ++sl) {
      int s = sl * 4 + (ln >> 4);
      boff[sl] = rB * 128 + (((s & 8) | ((s ^ rB) & 7)) << 3);
    }
  }

  f32x4 acc0 = {0.f, 0.f, 0.f, 0.f};
  f32x4 acc1 = {0.f, 0.f, 0.f, 0.f};

  auto stage = [&](int c, int b) {
    const int co = c * 256;            // uniform byte offset for all pieces
#pragma unroll
    for (int i = 0; i < 12; ++i) glds16(srcb[i] + co, &lds[b][ldsoff[i]]);
  };

  stage(0, 0);
#pragma unroll
  for (int c = 0; c < NCH; ++c) {
    const int b = c & 1;
    __builtin_amdgcn_s_barrier();               // prev compute done: buf b^1 free
    if (c < NCH - 1) {
      stage(c + 1, b ^ 1);
      asm volatile("s_waitcnt vmcnt(12)" ::: "memory");  // chunk c landed; c+1 in flight
    } else {
      asm volatile("s_waitcnt vmcnt(0)" ::: "memory");
    }
    __builtin_amdgcn_s_barrier();               // all waves see chunk c
#pragma unroll
    for (int sl = 0; sl < 4; ++sl) {
      short8 ahi0 = *(const short8*)&lds[b][AHI + aoff[0][sl]];
      short8 ahi1 = *(const short8*)&lds[b][AHI + aoff[1][sl]];
      short8 alo0 = *(const short8*)&lds[b][ALO + aoff[0][sl]];
      short8 alo1 = *(const short8*)&lds[b][ALO + aoff[1][sl]];
      short8 bhi  = *(const short8*)&lds[b][BHI + boff[sl]];
      short8 blo  = *(const short8*)&lds[b][BLO + boff[sl]];
      acc0 = __builtin_amdgcn_mfma_f32_16x16x32_bf16(ahi0, bhi, acc0, 0, 0, 0);
      acc0 = __builtin_amdgcn_mfma_f32_16x16x32_bf16(ahi0, blo, acc0, 0, 0, 0);
      acc0 = __builtin_amdgcn_mfma_f32_16x16x32_bf16(alo0, bhi, acc0, 0, 0, 0);
      acc1 = __builtin_amdgcn_mfma_f32_16x16x32_bf16(ahi1, bhi, acc1, 0, 0, 0);
      acc1 = __builtin_amdgcn_mfma_f32_16x16x32_bf16(ahi1, blo, acc1, 0, 0, 0);
      acc1 = __builtin_amdgcn_mfma_f32_16x16x32_bf16(alo1, bhi, acc1, 0, 0, 0);
    }
  }

  // ---- epilogue: fuse 4 gates (adjacent lanes) -> c,h ; emit h, c, h_hi/h_lo ----
  const int jj = j0 + w * 16 + (ln & 15);
  const float lamv = lamP[jj];
  const float biav = biasP[jj];
  const int rbase = (ln >> 4) * 4;
#pragma unroll
  for (int mf = 0; mf < 2; ++mf) {
    const int m0 = n0 + mf * 16 + rbase;
#pragma unroll
    for (int r = 0; r < 4; ++r) {
      const int m = m0 + r;
      float a = (mf == 0) ? acc0[r] : acc1[r];
      float v = sigf(a + sT[t * NN + m] * lamv + biav);
      const int base = ln & ~3;
      float vi = __shfl(v, base + 0, 64);
      float vf = __shfl(v, base + 1, 64);
      float vg = __shfl(v, base + 2, 64);
      float vo = __shfl(v, base + 3, 64);
      if ((ln & 3) == 0) {
        const int hc = jj >> 2;
        float cold = cbuf[m * HH + hc];
        float cn = vf * cold + vi * vg;
        float hn = vo * sigf(cn);
        cbuf[m * HH + hc] = cn;
        out[(size_t)m * (LL * HH) + (size_t)t * HH + hc] = hn;
        unsigned short h2 = f2bf(hn);
        Acur[(size_t)m * AK + hc] = h2;
        Acur[(size_t)m * AK + 1024 + hc] = f2bf(hn - bf2f(h2));
      }
    }
  }
}

extern "C" void kernel_launch(void* const* d_in, const int* in_sizes, int n_in,
                              void* d_out, int out_size, void* d_ws, size_t ws_size,
                              hipStream_t stream) {
  const float* X    = (const float*)d_in[0];
  const float* lami = (const float*)d_in[1];
  const float* bvi  = (const float*)d_in[2];
  const float* Wi   = (const float*)d_in[3];
  const float* bi   = (const float*)d_in[4];
  const float* lamf = (const float*)d_in[5];
  const float* bvf  = (const float*)d_in[6];
  const float* Wf   = (const float*)d_in[7];
  const float* bf_  = (const float*)d_in[8];
  const float* lamg = (const float*)d_in[9];
  const float* bvg  = (const float*)d_in[10];
  const float* Wg   = (const float*)d_in[11];
  const float* bg   = (const float*)d_in[12];
  const float* lamo = (const float*)d_in[13];
  const float* bvo  = (const float*)d_in[14];
  const float* Wo   = (const float*)d_in[15];
  const float* bo   = (const float*)d_in[16];

  float* out  = (float*)d_out;

  // workspace layout (~18.2 MB)
  float* cbuf  = (float*)d_ws;                         // 128*1024 f32
  float* sT    = cbuf + (size_t)NN * HH;               // 512*128  f32 (transposed s)
  float* lamP  = sT + (size_t)NN * LL;                 // 4096 f32
  float* biasP = lamP + NJ;                            // 4096 f32
  unsigned short* A0 = (unsigned short*)(biasP + NJ);  // 128*2048 bf16
  unsigned short* A1 = A0 + (size_t)NN * AK;           // 128*2048 bf16
  unsigned short* Bb = A1 + (size_t)NN * AK;           // 4096*2048 bf16 (16 MB)

  sum_rows_kernel<<<(NN * LL) / 4, 256, 0, stream>>>(X, sT);
  wsplit_kernel<<<(NJ * 128) / 256, 256, 0, stream>>>(Wi, Wf, Wg, Wo, Bb);
  pack_kernel<<<NJ / 256, 256, 0, stream>>>(lami, lamf, lamg, lamo,
                                            bvi, bvf, bvg, bvo,
                                            bi, bf_, bg, bo, lamP, biasP);
  t0_kernel<<<(NN * HH) / 256, 256, 0, stream>>>(sT, lamP, biasP, out, cbuf, A0);

  for (int t = 1; t < LL; ++t) {
    const unsigned short* Ap = (t & 1) ? A0 : A1;
    unsigned short* Ac = (t & 1) ? (unsigned short*)A1 : A0;
    step_kernel<<<256, 256, 0, stream>>>(Ap, Bb, sT, lamP, biasP, out, cbuf, Ac, t);
  }
}